// Round 8
// baseline (239.288 us; speedup 1.0000x reference)
//
#include <hip/hip_runtime.h>

// CenterLoss: out = mean_i sqrt( sum_d (x[i,d] - weight[targets[i],d])^2 + EPS )
// x: [N=65536, D=512] f32, weight: [C=1000, D=512] f32, targets: [N] i32.
//
// R8 = MEASUREMENT ROUND. R3/R5/R7 all land at dur_us ~200 and the kernel
// never shows in rocprof top-5 (so kernel < 77us), but harness reset traffic
// (~120-175us) makes the kernel's own time unobservable. This round launches
// the identical R5 kernel TWICE with inv_n/2 (same final result; absmax ~0).
// dur_2x - dur_1x == one kernel pass, measured on-chip:
//   ~+12us  -> pass2 L3-fast -> kernel is HBM-BW-bound at roofline -> declare
//   ~+65us  -> slowness replicates -> non-BW bottleneck, keep optimizing

typedef float f32x4 __attribute__((ext_vector_type(4)));

constexpr int D = 512;
constexpr float EPS = 1e-6f;
constexpr int RPW = 8;                 // rows per wave
constexpr int WPB = 4;                 // waves per block (256 threads)

__global__ __launch_bounds__(256) void centerloss_kernel(
    const float* __restrict__ x,
    const float* __restrict__ w,
    const int*   __restrict__ targets,
    float* __restrict__ out,
    int n_rows, float inv_n)
{
    const int lane = threadIdx.x & 63;
    const int wave = threadIdx.x >> 6;
    const int gw = blockIdx.x * WPB + wave;
    const long base = (long)gw * RPW;

    // One-shot target prefetch: lane k (k<8) holds targets[base+k].
    int tml = 0;
    {
        const long r = base + lane;
        if (lane < RPW && r < (long)n_rows) tml = targets[r];
    }

    float wsum = 0.0f;
    const f32x4 fz = {0.f, 0.f, 0.f, 0.f};

    #pragma unroll
    for (int k = 0; k < RPW; k += 2) {
        const long r0 = base + k;
        const long r1 = base + k + 1;
        const bool v0 = r0 < (long)n_rows;       // wave-uniform guards
        const bool v1 = r1 < (long)n_rows;
        const int t0 = __builtin_amdgcn_readlane(tml, k);
        const int t1 = __builtin_amdgcn_readlane(tml, k + 1);

        const f32x4* __restrict__ xr0 = reinterpret_cast<const f32x4*>(x + r0 * D);
        const f32x4* __restrict__ xr1 = reinterpret_cast<const f32x4*>(x + r1 * D);
        const f32x4* __restrict__ wr0 = reinterpret_cast<const f32x4*>(w + (size_t)t0 * D);
        const f32x4* __restrict__ wr1 = reinterpret_cast<const f32x4*>(w + (size_t)t1 * D);

        f32x4 xa0 = fz, xb0 = fz, wa0 = fz, wb0 = fz;
        f32x4 xa1 = fz, xb1 = fz, wa1 = fz, wb1 = fz;
        if (v0) {
            xa0 = __builtin_nontemporal_load(&xr0[lane]);
            xb0 = __builtin_nontemporal_load(&xr0[lane + 64]);
            wa0 = wr0[lane];
            wb0 = wr0[lane + 64];
        }
        if (v1) {
            xa1 = __builtin_nontemporal_load(&xr1[lane]);
            xb1 = __builtin_nontemporal_load(&xr1[lane + 64]);
            wa1 = wr1[lane];
            wb1 = wr1[lane + 64];
        }

        float a0 = 0.f, a1 = 0.f, d;
        d = xa0.x - wa0.x; a0 = fmaf(d, d, a0);
        d = xa0.y - wa0.y; a0 = fmaf(d, d, a0);
        d = xa0.z - wa0.z; a0 = fmaf(d, d, a0);
        d = xa0.w - wa0.w; a0 = fmaf(d, d, a0);
        d = xb0.x - wb0.x; a0 = fmaf(d, d, a0);
        d = xb0.y - wb0.y; a0 = fmaf(d, d, a0);
        d = xb0.z - wb0.z; a0 = fmaf(d, d, a0);
        d = xb0.w - wb0.w; a0 = fmaf(d, d, a0);

        d = xa1.x - wa1.x; a1 = fmaf(d, d, a1);
        d = xa1.y - wa1.y; a1 = fmaf(d, d, a1);
        d = xa1.z - wa1.z; a1 = fmaf(d, d, a1);
        d = xa1.w - wa1.w; a1 = fmaf(d, d, a1);
        d = xb1.x - wb1.x; a1 = fmaf(d, d, a1);
        d = xb1.y - wb1.y; a1 = fmaf(d, d, a1);
        d = xb1.z - wb1.z; a1 = fmaf(d, d, a1);
        d = xb1.w - wb1.w; a1 = fmaf(d, d, a1);

        #pragma unroll
        for (int off = 1; off < 64; off <<= 1) {
            a0 += __shfl_xor(a0, off, 64);
            a1 += __shfl_xor(a1, off, 64);
        }
        if (v0) wsum += sqrtf(a0 + EPS);
        if (v1) wsum += sqrtf(a1 + EPS);
    }

    __shared__ float smem[WPB];
    if (lane == 0) smem[wave] = wsum;
    __syncthreads();

    if (threadIdx.x == 0) {
        float s = 0.0f;
        #pragma unroll
        for (int i = 0; i < WPB; ++i) s += smem[i];
        atomicAdd(out, s * inv_n);      // pre-scaled contribution
    }
}

extern "C" void kernel_launch(void* const* d_in, const int* in_sizes, int n_in,
                              void* d_out, int out_size, void* d_ws, size_t ws_size,
                              hipStream_t stream) {
    const float* x       = (const float*)d_in[0];
    const float* weight  = (const float*)d_in[1];
    const int*   targets = (const int*)d_in[2];
    float* out = (float*)d_out;

    const int n_rows = in_sizes[2];   // 65536

    // d_out is poisoned to 0xAA before every call; zero it for the atomicAdd.
    (void)hipMemsetAsync(d_out, 0, sizeof(float), stream);

    const int rowsPerBlock = WPB * RPW;                 // 32
    const int grid = (n_rows + rowsPerBlock - 1) / rowsPerBlock;  // 2048

    // MEASUREMENT: identical kernel twice, each contributing half the mean.
    // dur_us delta vs single-launch (R6: 200.07) isolates one kernel pass.
    const float half_inv_n = 0.5f / (float)n_rows;
    centerloss_kernel<<<grid, 256, 0, stream>>>(x, weight, targets, out,
                                                n_rows, half_inv_n);
    centerloss_kernel<<<grid, 256, 0, stream>>>(x, weight, targets, out,
                                                n_rows, half_inv_n);
}

// Round 9
// 199.874 us; speedup vs baseline: 1.1972x; 1.1972x over previous
//
#include <hip/hip_runtime.h>

// CenterLoss: out = mean_i sqrt( sum_d (x[i,d] - weight[targets[i],d])^2 + EPS )
// x: [N=65536, D=512] f32, weight: [C=1000, D=512] f32, targets: [N] i32.
//
// R8 measurement: one kernel pass = 39us (dur 2x-1x), vs ~20us HBM floor at
// the 6.6-6.9 TB/s this box demonstrates. VALU/DS/TA budgets are all <7us,
// so the kernel is HBM-read-limited but below the achievable read ceiling.
// R9 theory: DRAM stream fragmentation — round-robin block->XCD dispatch
// scatters consecutive x-windows across XCDs. Fix: bijective XCD swizzle
// (T1): wg = (bid&7)*(nwg/8) + bid/8, so each XCD reads one contiguous
// 16 MB x-span. nwg=2048 % 8 == 0 -> bijective.

typedef float f32x4 __attribute__((ext_vector_type(4)));

constexpr int D = 512;
constexpr float EPS = 1e-6f;
constexpr int RPW = 8;                 // rows per wave
constexpr int WPB = 4;                 // waves per block (256 threads)

__global__ __launch_bounds__(256) void centerloss_kernel(
    const float* __restrict__ x,
    const float* __restrict__ w,
    const int*   __restrict__ targets,
    float* __restrict__ out,
    int n_rows, float inv_n)
{
    const int lane = threadIdx.x & 63;
    const int wave = threadIdx.x >> 6;

    // XCD-aware bijective swizzle: blocks with the same (bid & 7) run on the
    // same XCD (round-robin dispatch); give them a contiguous wg range so
    // each XCD streams one contiguous 16 MB slice of x.
    const int bid = blockIdx.x;
    const int chunk = gridDim.x >> 3;              // 2048/8 = 256
    const int wg = (bid & 7) * chunk + (bid >> 3);

    const int gw = wg * WPB + wave;
    const long base = (long)gw * RPW;

    // One-shot target prefetch: lane k (k<8) holds targets[base+k].
    int tml = 0;
    {
        const long r = base + lane;
        if (lane < RPW && r < (long)n_rows) tml = targets[r];
    }

    float wsum = 0.0f;
    const f32x4 fz = {0.f, 0.f, 0.f, 0.f};

    #pragma unroll
    for (int k = 0; k < RPW; k += 2) {
        const long r0 = base + k;
        const long r1 = base + k + 1;
        const bool v0 = r0 < (long)n_rows;       // wave-uniform guards
        const bool v1 = r1 < (long)n_rows;
        const int t0 = __builtin_amdgcn_readlane(tml, k);
        const int t1 = __builtin_amdgcn_readlane(tml, k + 1);

        const f32x4* __restrict__ xr0 = reinterpret_cast<const f32x4*>(x + r0 * D);
        const f32x4* __restrict__ xr1 = reinterpret_cast<const f32x4*>(x + r1 * D);
        const f32x4* __restrict__ wr0 = reinterpret_cast<const f32x4*>(w + (size_t)t0 * D);
        const f32x4* __restrict__ wr1 = reinterpret_cast<const f32x4*>(w + (size_t)t1 * D);

        f32x4 xa0 = fz, xb0 = fz, wa0 = fz, wb0 = fz;
        f32x4 xa1 = fz, xb1 = fz, wa1 = fz, wb1 = fz;
        if (v0) {
            xa0 = __builtin_nontemporal_load(&xr0[lane]);
            xb0 = __builtin_nontemporal_load(&xr0[lane + 64]);
            wa0 = wr0[lane];
            wb0 = wr0[lane + 64];
        }
        if (v1) {
            xa1 = __builtin_nontemporal_load(&xr1[lane]);
            xb1 = __builtin_nontemporal_load(&xr1[lane + 64]);
            wa1 = wr1[lane];
            wb1 = wr1[lane + 64];
        }

        float a0 = 0.f, a1 = 0.f, d;
        d = xa0.x - wa0.x; a0 = fmaf(d, d, a0);
        d = xa0.y - wa0.y; a0 = fmaf(d, d, a0);
        d = xa0.z - wa0.z; a0 = fmaf(d, d, a0);
        d = xa0.w - wa0.w; a0 = fmaf(d, d, a0);
        d = xb0.x - wb0.x; a0 = fmaf(d, d, a0);
        d = xb0.y - wb0.y; a0 = fmaf(d, d, a0);
        d = xb0.z - wb0.z; a0 = fmaf(d, d, a0);
        d = xb0.w - wb0.w; a0 = fmaf(d, d, a0);

        d = xa1.x - wa1.x; a1 = fmaf(d, d, a1);
        d = xa1.y - wa1.y; a1 = fmaf(d, d, a1);
        d = xa1.z - wa1.z; a1 = fmaf(d, d, a1);
        d = xa1.w - wa1.w; a1 = fmaf(d, d, a1);
        d = xb1.x - wb1.x; a1 = fmaf(d, d, a1);
        d = xb1.y - wb1.y; a1 = fmaf(d, d, a1);
        d = xb1.z - wb1.z; a1 = fmaf(d, d, a1);
        d = xb1.w - wb1.w; a1 = fmaf(d, d, a1);

        #pragma unroll
        for (int off = 1; off < 64; off <<= 1) {
            a0 += __shfl_xor(a0, off, 64);
            a1 += __shfl_xor(a1, off, 64);
        }
        if (v0) wsum += sqrtf(a0 + EPS);
        if (v1) wsum += sqrtf(a1 + EPS);
    }

    __shared__ float smem[WPB];
    if (lane == 0) smem[wave] = wsum;
    __syncthreads();

    if (threadIdx.x == 0) {
        float s = 0.0f;
        #pragma unroll
        for (int i = 0; i < WPB; ++i) s += smem[i];
        atomicAdd(out, s * inv_n);      // pre-scaled: out = mean
    }
}

extern "C" void kernel_launch(void* const* d_in, const int* in_sizes, int n_in,
                              void* d_out, int out_size, void* d_ws, size_t ws_size,
                              hipStream_t stream) {
    const float* x       = (const float*)d_in[0];
    const float* weight  = (const float*)d_in[1];
    const int*   targets = (const int*)d_in[2];
    float* out = (float*)d_out;

    const int n_rows = in_sizes[2];   // 65536

    // d_out is poisoned to 0xAA before every call; zero it for the atomicAdd.
    (void)hipMemsetAsync(d_out, 0, sizeof(float), stream);

    const int rowsPerBlock = WPB * RPW;                 // 32
    const int grid = (n_rows + rowsPerBlock - 1) / rowsPerBlock;  // 2048
    centerloss_kernel<<<grid, 256, 0, stream>>>(x, weight, targets, out,
                                                n_rows, 1.0f / (float)n_rows);
}